// Round 1
// baseline (3176.508 us; speedup 1.0000x reference)
//
#include <hip/hip_runtime.h>
#include <math.h>

#define BB 128
#define TT 32
#define DDIM 64
#define SS 32
#define VV 8192
#define MAXREC 8
#define NBLK 128
#define NTHR 256

// workspace byte offsets
#define OFF_GW     0u          // 2*128*128 f32 = 131072 B (double-buffered gw)
#define OFF_MEMR   131072u     // 128*32*64 f32 = 1048576 B
#define OFF_MEMI   1179648u    // 1048576 B
#define OFF_OUTH   2228224u    // 4096*128 f32 = 2097152 B (per-(b,t) gw output)
#define OFF_PART   4325376u    // 128*128 u64 = 131072 B (VQ partial mins)
#define OFF_ESQ    4456448u    // 8192 f32
#define OFF_PANG   4489216u    // 128*64 f32 (prev_ang)
#define OFF_ACT    4521984u    // 128 f32
#define OFF_ACC    4522496u    // 4*128 f32 (acc_vq, acc_ent, acc_pond, acc_ph)
#define OFF_RST    4524544u    // 128*4 f32 (per-row stat accum over t)
#define OFF_FLG    4526592u    // 16 u32 (any-active flag per iteration)
#define OFF_BAR    4526656u    // 2 u32 (grid barrier count, generation)

#define TWO_PI_F 6.283185307179586f

__device__ __forceinline__ float wredsum(float v) {
#pragma unroll
  for (int m = 32; m > 0; m >>= 1) v += __shfl_xor(v, m);
  return v;
}

__device__ __forceinline__ unsigned long long shflx64(unsigned long long v, int m) {
  int lo = __shfl_xor((int)(unsigned)(v & 0xffffffffull), m);
  int hi = __shfl_xor((int)(unsigned)(v >> 32), m);
  return ((unsigned long long)(unsigned)hi << 32) | (unsigned)lo;
}

// monotone float->u32 then pack with idx: u64 min == (min dist, then min idx) == jnp.argmin tie-break
__device__ __forceinline__ unsigned long long packkey(float d, unsigned c) {
  unsigned u = __float_as_uint(d);
  u = (u & 0x80000000u) ? ~u : (u | 0x80000000u);
  return ((unsigned long long)u << 32) | c;
}

__device__ __forceinline__ void grid_sync(unsigned* bar) {
  __syncthreads();
  if (threadIdx.x == 0) {
    __threadfence();
    unsigned g = __hip_atomic_load(&bar[1], __ATOMIC_RELAXED, __HIP_MEMORY_SCOPE_AGENT);
    unsigned a = __hip_atomic_fetch_add(&bar[0], 1u, __ATOMIC_ACQ_REL, __HIP_MEMORY_SCOPE_AGENT);
    if (a == (unsigned)(NBLK - 1)) {
      __hip_atomic_store(&bar[0], 0u, __ATOMIC_RELAXED, __HIP_MEMORY_SCOPE_AGENT);
      __hip_atomic_fetch_add(&bar[1], 1u, __ATOMIC_RELEASE, __HIP_MEMORY_SCOPE_AGENT);
    } else {
      while (__hip_atomic_load(&bar[1], __ATOMIC_ACQUIRE, __HIP_MEMORY_SCOPE_AGENT) == g) {
        __builtin_amdgcn_s_sleep(2);
      }
    }
    __threadfence();
  }
  __syncthreads();
}

__global__ void sacrsn_init(const float* __restrict__ vqe, char* __restrict__ ws) {
  float* gwb = (float*)(ws + OFF_GW);
  float* memr = (float*)(ws + OFF_MEMR);
  float* memi = (float*)(ws + OFF_MEMI);
  float* rst = (float*)(ws + OFF_RST);
  float* esq = (float*)(ws + OFF_ESQ);
  unsigned* flg = (unsigned*)(ws + OFF_FLG);
  unsigned* bar = (unsigned*)(ws + OFF_BAR);
  const int gt = blockIdx.x * blockDim.x + threadIdx.x;
  const int stride = gridDim.x * blockDim.x;
  for (int i = gt; i < 32768; i += stride) gwb[i] = 0.0f;
  for (int i = gt; i < 262144; i += stride) { memr[i] = 0.0f; memi[i] = 0.0f; }
  for (int i = gt; i < 512; i += stride) rst[i] = 0.0f;
  for (int i = gt; i < 16; i += stride) flg[i] = 0u;
  if (gt < 2) bar[gt] = 0u;
  for (int c = gt; c < VV; c += stride) {
    const float4* e = (const float4*)(vqe + ((size_t)c << 7));
    float s = 0.0f;
#pragma unroll 8
    for (int k = 0; k < 32; ++k) {
      float4 v = e[k];
      s = fmaf(v.x, v.x, fmaf(v.y, v.y, fmaf(v.z, v.z, fmaf(v.w, v.w, s))));
    }
    esq[c] = s;
  }
}

__global__ __launch_bounds__(NTHR) void sacrsn_main(
    const int* __restrict__ x_seq, const float* __restrict__ enc,
    const float* __restrict__ vqe,
    const float* __restrict__ nrg, const float* __restrict__ nrb,
    const float* __restrict__ nig, const float* __restrict__ nib,
    const float* __restrict__ qWr, const float* __restrict__ qbr,
    const float* __restrict__ qWi, const float* __restrict__ qbi,
    const float* __restrict__ gtw, const float* __restrict__ gtb,
    const float* __restrict__ aW, const float* __restrict__ ab,
    const float* __restrict__ hbp, const float* __restrict__ igp,
    float* __restrict__ dout, char* __restrict__ ws)
{
  float* gwbuf = (float*)(ws + OFF_GW);
  float* memr  = (float*)(ws + OFF_MEMR);
  float* memi  = (float*)(ws + OFF_MEMI);
  float* outh  = (float*)(ws + OFF_OUTH);
  unsigned long long* part = (unsigned long long*)(ws + OFF_PART);
  float* esq   = (float*)(ws + OFF_ESQ);
  float* pang  = (float*)(ws + OFF_PANG);
  float* act   = (float*)(ws + OFF_ACT);
  float* accb  = (float*)(ws + OFF_ACC);
  float* rst   = (float*)(ws + OFF_RST);
  unsigned* flg = (unsigned*)(ws + OFF_FLG);
  unsigned* bar = (unsigned*)(ws + OFF_BAR);

  const int tid = threadIdx.x;
  const int wv = tid >> 6, ln = tid & 63;
  const int blk = blockIdx.x;

  const float alpha = 1.0f / (1.0f + expf(-igp[0]));
  const float onema = 1.0f - alpha;
  const float hbias = log1pf(expf(hbp[0]));
  const float gtb0 = gtb[0];

  const float rgv = nrg[ln], rbv = nrb[ln], igv = nig[ln], ibv = nib[ln];
  const float gwl0 = gtw[ln], gwl1 = gtw[64 + ln];

  __shared__ float zf[8192];                 // 64 rows x 128, XOR-swizzled per 16B unit
  __shared__ float zfm[128];                 // this block's own row z_flat
  __shared__ float z2s[64];
  __shared__ unsigned long long vtmp[4][64];
  __shared__ unsigned idxall[128];
  __shared__ float qk[6][64];                // qr qi kr ki vr2 vi2
  __shared__ float simb[32];
  __shared__ float attnb[32];
  __shared__ float mrb[64], mib[64];
  __shared__ float entp[4];
  __shared__ float scal[8];                  // 0 gate, 1 vq_loss, 2 entropy, 3..5 arb gates

  for (int t = 0; t < TT; ++t) {
    float* gin  = gwbuf + ((t & 1) << 14);
    float* gout = gwbuf + (((t + 1) & 1) << 14);
    for (int it = 0; it < MAXREC; ++it) {
      if (it > 0) {
        if (__hip_atomic_load(&flg[it], __ATOMIC_RELAXED, __HIP_MEMORY_SCOPE_AGENT) == 0u)
          break;  // all rows inactive -> remaining iterations are exact no-ops
      }
      // ================= P1: (merge) + LN all rows + VQ partial argmin =================
      if (tid == 0 && blk == 0)
        __hip_atomic_store(&flg[it + 1], 0u, __ATOMIC_RELAXED, __HIP_MEMORY_SCOPE_AGENT);
      for (int pass = 0; pass < 2; ++pass) {
        for (int i = 0; i < 16; ++i) {
          const int r = pass * 64 + wv * 16 + i;
          const int lr = r - pass * 64;
          float gr, gi;
          if (it == 0) {
            float pr = gin[r * 128 + ln];
            float pi = gin[r * 128 + 64 + ln];
            int tok = x_seq[r * TT + t];
            gr = fmaf(alpha, pr, onema * enc[tok * 128 + ln]);
            gi = fmaf(alpha, pi, onema * enc[tok * 128 + 64 + ln]);
            if (blk == r) {  // block r's once-per-timestep row duties
              if (t > 0) {
                // mem_write for previous timestep (circular buffer: roll == head decrement)
                float wsum = wredsum(pr * gwl0 + pi * gwl1);
                float wg = 1.0f / (1.0f + expf(-(wsum + gtb0)));
                int slot = 32 - t;
                size_t mo = ((size_t)r * SS + slot) * DDIM + ln;
                memr[mo] = fmaf(wg, pr, (1.0f - wg) * memr[mo]);
                memi[mo] = fmaf(wg, pi, (1.0f - wg) * memi[mo]);
                size_t oo = ((size_t)r * TT + (t - 1)) * 128 + ln;
                outh[oo] = pr;
                outh[oo + 64] = pi;
                if (ln < 4) rst[r * 4 + ln] += accb[ln * 128 + r];  // flush stats of t-1
              }
              if (ln < 4) accb[ln * 128 + r] = 0.0f;
              if (ln == 0) act[r] = 1.0f;
              pang[r * 64 + ln] = atan2f(gi, gr);  // prev_ang init from merged gw
              gout[r * 128 + ln] = gr;
              gout[r * 128 + 64 + ln] = gi;
            }
          } else {
            gr = gout[r * 128 + ln];
            gi = gout[r * 128 + 64 + ln];
          }
          // LayerNorm (two-pass, matches reference formula)
          float mur = wredsum(gr) * 0.015625f;
          float xr = gr - mur;
          float vrr = wredsum(xr * xr) * 0.015625f;
          float cr = xr * (1.0f / sqrtf(vrr + 1e-5f)) * rgv + rbv;
          float mui = wredsum(gi) * 0.015625f;
          float xi = gi - mui;
          float vii = wredsum(xi * xi) * 0.015625f;
          float ci = xi * (1.0f / sqrtf(vii + 1e-5f)) * igv + ibv;
          zf[lr * 128 + ((((ln >> 2) ^ lr) & 31) << 2) + (ln & 3)] = cr;
          zf[lr * 128 + (((((64 + ln) >> 2) ^ lr) & 31) << 2) + (ln & 3)] = ci;
          float z2 = wredsum(fmaf(cr, cr, ci * ci));
          if (ln == 0) z2s[lr] = z2;
          if (blk == r) { zfm[ln] = cr; zfm[64 + ln] = ci; }
        }
        __syncthreads();
        // VQ distances: this block's 64-code slice x 64 rows of this pass
        {
          const int rt = tid & 31, ct = tid >> 5;
          const int c0 = blk * 64 + ct * 8;
          const int lr0 = rt, lr1 = rt + 32;
          float acc0[8], acc1[8];
#pragma unroll
          for (int j = 0; j < 8; ++j) { acc0[j] = 0.0f; acc1[j] = 0.0f; }
#pragma unroll 2
          for (int k4 = 0; k4 < 32; ++k4) {
            float4 a0 = *(const float4*)&zf[(lr0 << 7) + (((k4 ^ lr0) & 31) << 2)];
            float4 a1 = *(const float4*)&zf[(lr1 << 7) + (((k4 ^ lr1) & 31) << 2)];
#pragma unroll
            for (int j = 0; j < 8; ++j) {
              float4 e = *(const float4*)&vqe[((size_t)(c0 + j) << 7) + (k4 << 2)];
              acc0[j] = fmaf(a0.x, e.x, fmaf(a0.y, e.y, fmaf(a0.z, e.z, fmaf(a0.w, e.w, acc0[j]))));
              acc1[j] = fmaf(a1.x, e.x, fmaf(a1.y, e.y, fmaf(a1.z, e.z, fmaf(a1.w, e.w, acc1[j]))));
            }
          }
          float z20 = z2s[lr0], z21 = z2s[lr1];
          unsigned long long k0 = 0xffffffffffffffffull, k1 = 0xffffffffffffffffull;
#pragma unroll
          for (int j = 0; j < 8; ++j) {
            float es = esq[c0 + j];
            unsigned long long p0 = packkey(z20 - 2.0f * acc0[j] + es, (unsigned)(c0 + j));
            unsigned long long p1 = packkey(z21 - 2.0f * acc1[j] + es, (unsigned)(c0 + j));
            if (p0 < k0) k0 = p0;
            if (p1 < k1) k1 = p1;
          }
          unsigned long long o0 = shflx64(k0, 32); if (o0 < k0) k0 = o0;
          unsigned long long o1 = shflx64(k1, 32); if (o1 < k1) k1 = o1;
          if (ln < 32) { vtmp[wv][lr0] = k0; vtmp[wv][lr1] = k1; }
        }
        __syncthreads();
        if (tid < 64) {
          unsigned long long k = vtmp[0][tid];
#pragma unroll
          for (int w = 1; w < 4; ++w) { unsigned long long o = vtmp[w][tid]; if (o < k) k = o; }
          part[((size_t)blk << 7) + pass * 64 + tid] = k;
        }
        __syncthreads();
      } // pass
      grid_sync(bar);
      // ================= P2: reduce argmin (all rows) + entropy + row update =================
      if (tid < 128) {
        unsigned long long k = part[tid];
        for (int j = 1; j < 128; ++j) {
          unsigned long long o = part[((size_t)j << 7) + tid];
          if (o < k) k = o;
        }
        idxall[tid] = (unsigned)k;
      }
      __syncthreads();
      if (tid < 192) {
        float term = 0.0f;
        if (tid < 128) {
          unsigned my = idxall[tid];
          int c = 0;
          for (int j = 0; j < 128; ++j) c += (idxall[j] == my) ? 1 : 0;
          term = -0.0078125f * logf((float)c * 0.0078125f + 1e-10f);
        }
        float s = wredsum(term);
        if (ln == 0) entp[wv] = s;
        // complex linear for q,k,v: thread = (head h, out dim j)
        const int h = tid >> 6, j = tid & 63;
        const float* wr = qWr + h * 4096 + j * 64;
        const float* wi = qWi + h * 4096 + j * 64;
        float da = 0.0f, dbm = 0.0f, dc = 0.0f, de = 0.0f;
        for (int d = 0; d < 64; ++d) {
          float crd = zfm[d], cid = zfm[64 + d];
          float wrd = wr[d], wid = wi[d];
          da = fmaf(crd, wrd, da);
          dbm = fmaf(cid, wid, dbm);
          dc = fmaf(cid, wrd, dc);
          de = fmaf(crd, wid, de);
        }
        float brv = qbr[h * 64 + j], biv = qbi[h * 64 + j];
        qk[2 * h][j] = da + brv - dbm - biv;
        qk[2 * h + 1][j] = dc + brv + de + biv;
      } else if (tid < 224) {
        const int s = tid - 192;
        const float* mr = memr + ((size_t)blk * SS + s) * DDIM;
        const float* mi = memi + ((size_t)blk * SS + s) * DDIM;
        float a2 = 0.0f;
        for (int d = 0; d < 64; ++d) a2 = fmaf(mr[d], zfm[d], fmaf(mi[d], zfm[64 + d], a2));
        simb[s] = a2;
      } else if (tid < 227) {
        const int h = tid - 224;
        float a2 = ab[h];
        for (int k2 = 0; k2 < 128; ++k2) a2 = fmaf(zfm[k2], aW[h * 128 + k2], a2);
        scal[3 + h] = a2;
      } else if (tid == 227) {
        unsigned ii = idxall[blk];
        const float* zq = vqe + ((size_t)ii << 7);
        float sacc = 0.0f;
        for (int k2 = 0; k2 < 128; ++k2) { float dl = zq[k2] - zfm[k2]; sacc = fmaf(dl, dl, sacc); }
        scal[1] = 1.25f * sacc * 0.0078125f;
      }
      __syncthreads();
      if (tid == 0) scal[2] = entp[0] + entp[1] + entp[2];
      if (tid < 64) {
        float p = fmaf(qk[0][tid], qk[2][tid], qk[1][tid] * qk[3][tid]);
        float s = wredsum(p);
        if (tid == 0) scal[0] = 1.0f / (1.0f + expf(-s));
      } else if (tid < 96) {
        const int s = tid - 64;
        float v = simb[s];
        float m = v;
#pragma unroll
        for (int msk = 16; msk > 0; msk >>= 1) m = fmaxf(m, __shfl_xor(m, msk));
        float e = expf(v - m);
        float ss = e;
#pragma unroll
        for (int msk = 16; msk > 0; msk >>= 1) ss += __shfl_xor(ss, msk);
        attnb[s] = e / ss;
      } else if (tid == 96) {
        float a0 = scal[3], a1 = scal[4], a2 = scal[5];
        float m = fmaxf(a0, fmaxf(a1, a2));
        float e0 = expf(a0 - m), e1 = expf(a1 - m), e2 = expf(a2 - m);
        float s = e0 + e1 + e2;
        scal[3] = e0 / s; scal[4] = e1 / s; scal[5] = e2 / s;
      }
      __syncthreads();
      if (tid < 64) {
        float a2 = 0.0f;
        const float* mr = memr + (size_t)blk * SS * DDIM + tid;
        for (int s2 = 0; s2 < 32; ++s2) a2 = fmaf(attnb[s2], mr[s2 * DDIM], a2);
        mrb[tid] = a2;
      } else if (tid < 128) {
        const int d = tid - 64;
        float a2 = 0.0f;
        const float* mi = memi + (size_t)blk * SS * DDIM + d;
        for (int s2 = 0; s2 < 32; ++s2) a2 = fmaf(attnb[s2], mi[s2 * DDIM], a2);
        mib[d] = a2;
      }
      __syncthreads();
      if (tid < 64) {
        const int d = tid;
        float aold = act[blk];
        bool mf = aold > 0.5f;
        unsigned ii = idxall[blk];
        float zqr = vqe[((size_t)ii << 7) + d];
        float zqi = vqe[((size_t)ii << 7) + 64 + d];
        float gate = scal[0], g0 = scal[3], g1 = scal[4], g2 = scal[5];
        float ur = fmaf(g0, qk[4][d] * gate, fmaf(g1, mrb[d], g2 * zqr));
        float ui = fmaf(g0, qk[5][d] * gate, fmaf(g1, mib[d], g2 * zqi));
        float cr = zfm[d], ci = zfm[64 + d];
        float cdr = fmaf(0.4f, ur, 0.6f * cr);
        float cdi = fmaf(0.4f, ui, 0.6f * ci);
        float ang = atan2f(cdi, cdr);
        float pa = pang[blk * 64 + d];
        float df = fabsf(ang - pa);
        df = fminf(df, TWO_PI_F - df);
        pang[blk * 64 + d] = ang;
        float dmean = wredsum(df) * 0.015625f;
        if (mf) {
          gout[blk * 128 + d] = cdr;
          gout[blk * 128 + 64 + d] = cdi;
        }
        if (d == 0) {
          float vql = scal[1];
          accb[3 * 128 + blk] += aold * dmean;   // acc_ph
          accb[2 * 128 + blk] += aold * 0.01f;   // acc_pond
          if (mf) {
            accb[0 * 128 + blk] = vql;           // acc_vq
            accb[1 * 128 + blk] = scal[2];       // acc_ent
            dout[(size_t)BB * TT * VV + 4 + (size_t)blk * TT + t] = (float)ii;  // fin_idx
          }
          bool stop = (hbias - vql) > 0.0f;
          float anew = stop ? 0.0f : aold;
          act[blk] = anew;
          if (anew > 0.5f) atomicOr(&flg[it + 1], 1u);
        }
      }
      grid_sync(bar);
    } // it
  } // t
  // final: out for t=31 (final gw is in buffer 0 since T is even) + flush t=31 stats
  if (tid < 64) {
    size_t oo = ((size_t)blk * TT + (TT - 1)) * 128 + tid;
    outh[oo] = gwbuf[blk * 128 + tid];
    outh[oo + 64] = gwbuf[blk * 128 + 64 + tid];
  }
  if (tid < 4) rst[blk * 4 + tid] += accb[tid * 128 + blk];
}

__global__ __launch_bounds__(256) void sacrsn_dec(
    const float* __restrict__ dW, const float* __restrict__ dbv,
    float* __restrict__ dout, const char* __restrict__ ws)
{
  const float* outh = (const float*)(ws + OFF_OUTH);
  const float* rst = (const float*)(ws + OFF_RST);
  __shared__ float As[4096];
  __shared__ float Bs[4096];
  const int tid = threadIdx.x;
  const int bx = blockIdx.x & 127;   // N tile (V)
  const int by = blockIdx.x >> 7;    // M tile (B*T)
  const int n0 = bx << 6, m0 = by << 6;
  if (blockIdx.x == 0 && tid < 4) {  // deterministic stats reduction
    float s = 0.0f;
    for (int r = 0; r < 128; ++r) s += rst[r * 4 + tid];
    dout[(size_t)BB * TT * VV + tid] = s * (1.0f / 4096.0f);
  }
  const int ty = tid >> 4, tx = tid & 15;
  float acc[4][4];
#pragma unroll
  for (int i = 0; i < 4; ++i)
#pragma unroll
    for (int j = 0; j < 4; ++j) acc[i][j] = 0.0f;
  for (int kh = 0; kh < 2; ++kh) {
    for (int u = tid; u < 1024; u += 256) {
      const int row = u >> 4, un = u & 15;
      const int sw = ((un ^ row) & 15) << 2;
      *(float4*)&As[(row << 6) + sw] =
          *(const float4*)&outh[((size_t)(m0 + row) << 7) + (kh << 6) + (un << 2)];
      *(float4*)&Bs[(row << 6) + sw] =
          *(const float4*)&dW[((size_t)(n0 + row) << 7) + (kh << 6) + (un << 2)];
    }
    __syncthreads();
#pragma unroll 4
    for (int k4 = 0; k4 < 16; ++k4) {
      float4 a[4], b[4];
#pragma unroll
      for (int ii = 0; ii < 4; ++ii) {
        const int row = (ty << 2) + ii;
        a[ii] = *(const float4*)&As[(row << 6) + (((k4 ^ row) & 15) << 2)];
      }
#pragma unroll
      for (int jj = 0; jj < 4; ++jj) {
        const int row = (tx << 2) + jj;
        b[jj] = *(const float4*)&Bs[(row << 6) + (((k4 ^ row) & 15) << 2)];
      }
#pragma unroll
      for (int ii = 0; ii < 4; ++ii)
#pragma unroll
        for (int jj = 0; jj < 4; ++jj)
          acc[ii][jj] = fmaf(a[ii].x, b[jj].x, fmaf(a[ii].y, b[jj].y,
                        fmaf(a[ii].z, b[jj].z, fmaf(a[ii].w, b[jj].w, acc[ii][jj]))));
    }
    __syncthreads();
  }
#pragma unroll
  for (int ii = 0; ii < 4; ++ii) {
    const int m = m0 + (ty << 2) + ii;
    const int v0 = n0 + (tx << 2);
    float4 o;
    o.x = acc[ii][0] + dbv[v0];
    o.y = acc[ii][1] + dbv[v0 + 1];
    o.z = acc[ii][2] + dbv[v0 + 2];
    o.w = acc[ii][3] + dbv[v0 + 3];
    *(float4*)&dout[((size_t)m << 13) + v0] = o;
  }
}

extern "C" void kernel_launch(void* const* d_in, const int* in_sizes, int n_in,
                              void* d_out, int out_size, void* d_ws, size_t ws_size,
                              hipStream_t stream) {
  (void)in_sizes; (void)n_in; (void)out_size; (void)ws_size;
  const int*   x_seq = (const int*)d_in[0];
  const float* enc = (const float*)d_in[1];
  const float* vq  = (const float*)d_in[2];
  const float* nrg = (const float*)d_in[3];
  const float* nrb = (const float*)d_in[4];
  const float* nig = (const float*)d_in[5];
  const float* nib = (const float*)d_in[6];
  const float* qWr = (const float*)d_in[7];
  const float* qbr = (const float*)d_in[8];
  const float* qWi = (const float*)d_in[9];
  const float* qbi = (const float*)d_in[10];
  const float* gtw = (const float*)d_in[11];
  const float* gtb = (const float*)d_in[12];
  const float* aW  = (const float*)d_in[13];
  const float* ab  = (const float*)d_in[14];
  const float* dW  = (const float*)d_in[15];
  const float* db  = (const float*)d_in[16];
  const float* hb  = (const float*)d_in[17];
  const float* ig  = (const float*)d_in[18];
  char* ws = (char*)d_ws;
  float* out = (float*)d_out;
  hipLaunchKernelGGL(sacrsn_init, dim3(64), dim3(256), 0, stream, vq, ws);
  hipLaunchKernelGGL(sacrsn_main, dim3(NBLK), dim3(NTHR), 0, stream,
                     x_seq, enc, vq, nrg, nrb, nig, nib, qWr, qbr, qWi, qbi,
                     gtw, gtb, aW, ab, hb, ig, out, ws);
  hipLaunchKernelGGL(sacrsn_dec, dim3(8192), dim3(256), 0, stream, dW, db, out, ws);
}